// Round 2
// baseline (1332.668 us; speedup 1.0000x reference)
//
#include <hip/hip_runtime.h>
#include <hip/hip_bf16.h>

#define NN 32768
#define DEG 8
#define PW 552          // P table row width (elements)
#define PTW 556         // padded LDS width for P tile

typedef unsigned short u16;
typedef unsigned int u32;

__device__ __forceinline__ float bf2f(u32 lo16) { return __uint_as_float(lo16 << 16); }

// ---------------- dtype detection ----------------
__global__ void detect_kernel(const void* __restrict__ x, int* __restrict__ flagp) {
  if (threadIdx.x == 0) {
    const u16* u = (const u16*)x;
    int insane = 0;
    for (int i = 0; i < 128; ++i) {
      int e = (u[i] >> 7) & 0xff;
      if (e == 0 || e == 0xff || e < 0x70 || e > 0x8f) insane++;
    }
    *flagp = (insane >= 16) ? 0 : 1;   // 1 = bf16 inputs, 0 = f32 inputs
  }
}

// ---------------- input conversion ----------------
__global__ void cvt_kernel(const void* __restrict__ src, float* __restrict__ dst, int n,
                           const int* __restrict__ flagp) {
  const int f = *flagp;
  for (int i = blockIdx.x * 256 + threadIdx.x; i < n; i += gridDim.x * 256) {
    if (f) dst[i] = bf2f((u32)((const u16*)src)[i]);
    else   dst[i] = ((const float*)src)[i];
  }
}

// ---------------- derived weight tables ----------------
// one block per head hd = l*2+t
__global__ __launch_bounds__(256) void derive_kernel(
    const float* __restrict__ qw, const float* __restrict__ qb,
    const float* __restrict__ ow, const float* __restrict__ ob,
    float* __restrict__ Mqk, float* __restrict__ Mvo,
    float* __restrict__ cq, float* __restrict__ ck, float* __restrict__ cvo,
    float* __restrict__ cc, float* __restrict__ bo_sum) {
  const int hd = blockIdx.x;                // 0..3
  const float* Wq = qw + (size_t)(hd*3 + 0) * 18769;
  const float* Wk = qw + (size_t)(hd*3 + 1) * 18769;
  const float* Wv = qw + (size_t)(hd*3 + 2) * 18769;
  const float* bq = qb + (hd*3 + 0) * 137;
  const float* bk = qb + (hd*3 + 1) * 137;
  const float* bv = qb + (hd*3 + 2) * 137;
  const float* Wo = ow + (size_t)hd * 18769;
  const int tid = threadIdx.x;

  for (int idx = tid; idx < 9*137; idx += 256) {
    int s = idx / 137, e = idx % 137;
    cq[hd*1233 + idx] = Wq[e*137 + 128 + s] + bq[e];
    ck[hd*1233 + idx] = Wk[e*137 + 128 + s] + bk[e];
  }
  __syncthreads();   // cc below reads cq/ck

  for (int idx = tid; idx < 128*128; idx += 256) {
    int row = idx >> 7, col = idx & 127;
    float sq = 0.f, so = 0.f;
    for (int e = 0; e < 137; ++e) {
      sq += Wq[e*137 + row] * Wk[e*137 + col];     // Mqk[c][c']
      so += Wo[row*137 + e] * Wv[e*137 + col];     // Mvo[oi][c]
    }
    Mqk[hd*16384 + idx] = sq;
    Mvo[hd*16384 + idx] = so;
  }
  for (int idx = tid; idx < 9*128; idx += 256) {
    int s = idx >> 7, oi = idx & 127;
    float a = 0.f;
    for (int e = 0; e < 137; ++e) a += Wo[oi*137 + e] * (Wv[e*137 + 128 + s] + bv[e]);
    cvo[hd*1152 + idx] = a;
  }
  for (int idx = tid; idx < 81; idx += 256) {
    int i = idx / 9, j = idx % 9;
    float a = 0.f;
    for (int e = 0; e < 137; ++e) a += cq[hd*1233 + i*137 + e] * ck[hd*1233 + j*137 + e];
    cc[hd*81 + idx] = a;
  }
  if ((hd & 1) == 0) {
    int l = hd >> 1;
    for (int oi = tid; oi < 128; oi += 256)
      bo_sum[l*128 + oi] = ob[(l*2 + 0)*137 + oi] + ob[(l*2 + 1)*137 + oi];
  }
}

// BigW[l][k][col], 128 x PW per layer
__global__ void bigw_kernel(const float* __restrict__ qw,
                            const float* __restrict__ Mqk, const float* __restrict__ Mvo,
                            const float* __restrict__ cq, const float* __restrict__ ck,
                            float* __restrict__ BigW) {
  const int idx = blockIdx.x * 256 + threadIdx.x;
  if (idx >= 2 * 128 * PW) return;
  const int l = idx / (128 * PW);
  const int r = idx % (128 * PW);
  const int k = r / PW, col = r % PW;
  float v = 0.f;
  if (col < 128)       v = Mqk[(l*2 + 0)*16384 + k*128 + col];
  else if (col < 256)  v = Mvo[(l*2 + 0)*16384 + (col - 128)*128 + k];
  else if (col < 384)  v = Mqk[(l*2 + 1)*16384 + k*128 + (col - 256)];
  else if (col < 512)  v = Mvo[(l*2 + 1)*16384 + (col - 384)*128 + k];
  else if (col < 530) {                       // qk_q: Hq_t . ck[t][j], linear in h
    int t = (col - 512) / 9, j = (col - 512) % 9;
    const float* Wq = qw + (size_t)((l*2 + t)*3 + 0) * 18769;
    const float* ckp = ck + (l*2 + t)*1233 + j*137;
    float a = 0.f;
    for (int e = 0; e < 137; ++e) a += Wq[e*137 + k] * ckp[e];
    v = a;
  } else if (col < 548) {                     // qk_k: cq[t][i] . Hk_t
    int t = (col - 530) / 9, i = (col - 530) % 9;
    const float* Wk_ = qw + (size_t)((l*2 + t)*3 + 1) * 18769;
    const float* cqp = cq + (l*2 + t)*1233 + i*137;
    float a = 0.f;
    for (int e = 0; e < 137; ++e) a += cqp[e] * Wk_[e*137 + k];
    v = a;
  }
  BigW[idx] = v;
}

// ---------------- generic f32 GEMM: C = A(MxK) @ B(KxNC), f32 out ----------------
__global__ __launch_bounds__(256) void gemm_kernel(
    const float* __restrict__ A, const float* __restrict__ B,
    float* __restrict__ C,
    int M, int K, int NC, int lda, int ldb, int ldc) {
  __shared__ float As[64][33];
  __shared__ float Bs[32][68];
  const int row0 = blockIdx.y * 64, col0 = blockIdx.x * 64;
  const int tid = threadIdx.x;
  const int tx = tid & 15, ty = tid >> 4;
  float acc[4][4] = {};
  for (int k0 = 0; k0 < K; k0 += 32) {
    {
      const int ka = tid & 31, ra = tid >> 5;
      const int kg = k0 + ka;
      #pragma unroll
      for (int p = 0; p < 8; ++p) {
        const int r = ra * 8 + p;
        As[r][ka] = (kg < K) ? A[(size_t)(row0 + r) * lda + kg] : 0.f;
      }
      const int cb = tid & 63, kb = tid >> 6;
      const int cg = col0 + cb;
      #pragma unroll
      for (int p = 0; p < 8; ++p) {
        const int kk = kb * 8 + p;
        const int kg2 = k0 + kk;
        Bs[kk][cb] = (kg2 < K && cg < NC) ? B[(size_t)kg2 * ldb + cg] : 0.f;
      }
    }
    __syncthreads();
    #pragma unroll
    for (int kk = 0; kk < 32; ++kk) {
      const float4 b4 = *(const float4*)&Bs[kk][tx * 4];
      float a[4];
      #pragma unroll
      for (int i = 0; i < 4; ++i) a[i] = As[ty*4 + i][kk];
      #pragma unroll
      for (int i = 0; i < 4; ++i) {
        acc[i][0] += a[i] * b4.x;
        acc[i][1] += a[i] * b4.y;
        acc[i][2] += a[i] * b4.z;
        acc[i][3] += a[i] * b4.w;
      }
    }
    __syncthreads();
  }
  #pragma unroll
  for (int i = 0; i < 4; ++i) {
    const int rr = row0 + ty*4 + i;
    #pragma unroll
    for (int j = 0; j < 4; ++j) {
      const int c = col0 + tx*4 + j;
      if (c < NC) C[(size_t)rr * ldc + c] = acc[i][j];
    }
  }
}

// ---------------- per-node fused attention ----------------
__global__ __launch_bounds__(256) void attn_kernel(
    const int* __restrict__ src, const float* __restrict__ hG, const float* __restrict__ PG,
    const float* __restrict__ cvo, const float* __restrict__ cc,
    const float* __restrict__ bo_sum, const float* __restrict__ b_layer,
    int layer, float* __restrict__ res) {
  __shared__ float Pt[9][PTW];
  __shared__ float hs[9][132];
  __shared__ float As[2][9][9];
  __shared__ float ymax[2][128];
  __shared__ int nbr[9];
  const int n = blockIdx.x;
  const int tid = threadIdx.x;
  if (tid < 9) nbr[tid] = (tid < 8) ? src[n * DEG + tid] : n;
  __syncthreads();
  for (int idx = tid; idx < 9 * 32; idx += 256) {
    const int s = idx >> 5, w = idx & 31;
    *(float4*)&hs[s][w * 4] = *(const float4*)(hG + (size_t)nbr[s] * 128 + w * 4);
  }
  for (int idx = tid; idx < 9 * 138; idx += 256) {
    const int s = idx / 138, w = idx % 138;
    *(float4*)&Pt[s][w * 4] = *(const float4*)(PG + (size_t)nbr[s] * PW + w * 4);
  }
  __syncthreads();
  if (tid < 162) {
    const int t = tid / 81, r = tid % 81, i = r / 9, j = r % 9;
    const float* hm = &Pt[i][t * 256];
    const float* hj = &hs[j][0];
    float s = 0.f;
    #pragma unroll 8
    for (int c = 0; c < 128; c += 4) {
      const float4 a = *(const float4*)&hm[c];
      const float4 b = *(const float4*)&hj[c];
      s += a.x * b.x + a.y * b.y + a.z * b.z + a.w * b.w;
    }
    s += Pt[i][512 + t*9 + j] + Pt[j][530 + t*9 + i] + cc[(layer*2 + t)*81 + i*9 + j];
    As[t][i][j] = s * 0.08543576577f;   // 1/sqrt(137)
  }
  __syncthreads();
  if (tid < 18) {
    const int t = tid / 9, i = tid % 9;
    float m = -3e38f;
    #pragma unroll
    for (int j = 0; j < 9; ++j) m = fmaxf(m, As[t][i][j]);
    float ex[9], ssum = 0.f;
    #pragma unroll
    for (int j = 0; j < 9; ++j) { ex[j] = expf(As[t][i][j] - m); ssum += ex[j]; }
    const float inv = 1.f / ssum;
    #pragma unroll
    for (int j = 0; j < 9; ++j) As[t][i][j] = ex[j] * inv;
  }
  __syncthreads();
  {
    const int oi = tid & 127, half = tid >> 7;
    const float* cvo1 = cvo + (layer*2 + 0)*1152 + oi;
    const float* cvo2 = cvo + (layer*2 + 1)*1152 + oi;
    float vg1[9], vg2[9];
    #pragma unroll
    for (int j = 0; j < 9; ++j) {
      vg1[j] = Pt[j][128 + oi] + cvo1[j * 128];
      vg2[j] = Pt[j][384 + oi] + cvo2[j * 128];
    }
    float mx = -3e38f;
    const int i0 = half ? 5 : 0, i1 = half ? 9 : 5;
    for (int i = i0; i < i1; ++i) {
      float y = hs[i][oi];
      #pragma unroll
      for (int j = 0; j < 9; ++j)
        y += As[0][i][j] * vg1[j] + As[1][i][j] * vg2[j];
      mx = fmaxf(mx, y);
    }
    ymax[half][oi] = mx;
  }
  __syncthreads();
  if (tid < 128) {
    const float v = fmaxf(ymax[0][tid], ymax[1][tid]) + bo_sum[layer*128 + tid] + b_layer[tid];
    res[(size_t)n * 128 + tid] = v;
  }
}

// ---------------- pairnorm reductions ----------------
__global__ __launch_bounds__(256) void reduce_kernel(const float* __restrict__ res,
                                                     float* __restrict__ partial) {
  __shared__ float col2[128];
  __shared__ float sqs[256];
  const int b = blockIdx.x, tid = threadIdx.x;
  const int c = tid & 127, half = tid >> 7;
  float cs = 0.f, sq = 0.f;
  const int r0 = half * 64;
  for (int r = r0; r < r0 + 64; ++r) {
    const float v = res[((size_t)b * 128 + r) * 128 + c];
    cs += v; sq += v * v;
  }
  if (half) col2[c] = cs;
  sqs[tid] = sq;
  __syncthreads();
  if (!half) partial[b * 129 + c] = cs + col2[c];
  for (int s = 128; s >= 1; s >>= 1) {
    if (tid < s) sqs[tid] += sqs[tid + s];
    __syncthreads();
  }
  if (tid == 0) partial[b * 129 + 128] = sqs[0];
}

__global__ __launch_bounds__(128) void finalize_kernel(const float* __restrict__ partial,
                                                       float* __restrict__ stats) {
  __shared__ float musq[128];
  __shared__ float sqs[128];
  const int tid = threadIdx.x;
  float cs = 0.f;
  for (int b = 0; b < 256; ++b) cs += partial[b * 129 + tid];
  const float m = cs * (1.f / 32768.f);
  stats[tid] = m;
  musq[tid] = m * m;
  float sq = 0.f;
  for (int b = tid; b < 256; b += 128) sq += partial[b * 129 + 128];
  sqs[tid] = sq;
  __syncthreads();
  for (int s = 64; s >= 1; s >>= 1) {
    if (tid < s) { musq[tid] += musq[tid + s]; sqs[tid] += sqs[tid + s]; }
    __syncthreads();
  }
  if (tid == 0) {
    const float meansq = sqs[0] * (1.f / 32768.f);
    const float var = meansq - musq[0];
    stats[128] = 1.f / sqrtf(1e-6f + var);
  }
}

__global__ void norm_relu_kernel(const float* __restrict__ res, const float* __restrict__ stats,
                                 float* __restrict__ u) {
  const int idx = blockIdx.x * 256 + threadIdx.x;
  const int c = idx & 127;
  const float v = (res[idx] - stats[c]) * stats[128];
  u[idx] = fmaxf(v, 0.f);
}

__global__ void final_kernel(const float* __restrict__ res, const float* __restrict__ stats,
                             const float* __restrict__ xf, void* __restrict__ out,
                             const int* __restrict__ flagp) {
  const int idx = blockIdx.x * 256 + threadIdx.x;
  const int nrow = idx >> 7, c = idx & 127;
  float v = fmaxf((res[idx] - stats[c]) * stats[128], 0.f);
  v += xf[(size_t)nrow * 130 + c];
  if (c == 127 && (v > 1.f || v < -1.f)) v = 0.f;
  v *= 0.5f;
  if (*flagp) ((__hip_bfloat16*)out)[idx] = __float2bfloat16(v);
  else        ((float*)out)[idx] = v;
}

// ---------------- host ----------------
extern "C" void kernel_launch(void* const* d_in, const int* in_sizes, int n_in,
                              void* d_out, int out_size, void* d_ws, size_t ws_size,
                              hipStream_t stream) {
  (void)in_sizes; (void)n_in; (void)out_size; (void)ws_size;
  char* ws = (char*)d_ws;
  size_t off = 0;
  auto alloc = [&](size_t bytes) -> char* {
    char* p = ws + off;
    off += (bytes + 255) & ~(size_t)255;
    return p;
  };
  int*   flagp = (int*)  alloc(4);
  float* xf    = (float*)alloc((size_t)NN * 130 * 4);
  float* W1f   = (float*)alloc(130 * 128 * 4);
  float* b1f   = (float*)alloc(128 * 4);
  float* W2f   = (float*)alloc(128 * 128 * 4);
  float* b2f   = (float*)alloc(128 * 4);
  float* qwf   = (float*)alloc((size_t)225228 * 4);
  float* qbf   = (float*)alloc(1644 * 4);
  float* owf   = (float*)alloc((size_t)75076 * 4);
  float* obf   = (float*)alloc(548 * 4);
  float* Mqk   = (float*)alloc((size_t)4 * 16384 * 4);
  float* Mvo   = (float*)alloc((size_t)4 * 16384 * 4);
  float* cq    = (float*)alloc((size_t)4 * 1233 * 4);
  float* ck    = (float*)alloc((size_t)4 * 1233 * 4);
  float* cvo   = (float*)alloc((size_t)4 * 1152 * 4);
  float* cc    = (float*)alloc((size_t)4 * 81 * 4);
  float* boS   = (float*)alloc((size_t)2 * 128 * 4);
  float* BigW  = (float*)alloc((size_t)2 * 128 * PW * 4);
  float* hbuf  = (float*)alloc((size_t)NN * 128 * 4);
  float* P     = (float*)alloc((size_t)NN * PW * 4);
  float* res   = (float*)alloc((size_t)NN * 128 * 4);
  float* ubuf  = (float*)alloc((size_t)NN * 128 * 4);
  float* part  = (float*)alloc((size_t)256 * 129 * 4);
  float* st0   = (float*)alloc(132 * 4);
  float* st1   = (float*)alloc(132 * 4);

  const int* edge = (const int*)d_in[1];   // row 0 = src

  detect_kernel<<<1, 64, 0, stream>>>(d_in[0], flagp);

  struct CvtDesc { const void* src; float* dst; int n; };
  const CvtDesc cv[9] = {
    { d_in[0], xf,  NN * 130 },
    { d_in[2], W1f, 130 * 128 },
    { d_in[3], b1f, 128 },
    { d_in[4], W2f, 128 * 128 },
    { d_in[5], b2f, 128 },
    { d_in[6], qwf, 225228 },
    { d_in[7], qbf, 1644 },
    { d_in[8], owf, 75076 },
    { d_in[9], obf, 548 },
  };
  for (int i = 0; i < 9; ++i) {
    int blocks = (cv[i].n + 255) / 256;
    if (blocks > 4096) blocks = 4096;
    cvt_kernel<<<blocks, 256, 0, stream>>>(cv[i].src, cv[i].dst, cv[i].n, flagp);
  }

  derive_kernel<<<4, 256, 0, stream>>>(qwf, qbf, owf, obf, Mqk, Mvo, cq, ck, cvo, cc, boS);
  bigw_kernel<<<(2 * 128 * PW + 255) / 256, 256, 0, stream>>>(qwf, Mqk, Mvo, cq, ck, BigW);

  for (int l = 0; l < 2; ++l) {
    const float* act = l ? ubuf : xf;
    const int K = l ? 128 : 130;
    const float* W = l ? W2f : W1f;
    // h = act @ W
    gemm_kernel<<<dim3(2, 512), 256, 0, stream>>>(act, W, hbuf,
                                                  NN, K, 128, K, 128, 128);
    // P = h @ BigW_l   (f32 out)
    gemm_kernel<<<dim3((PW + 63) / 64, 512), 256, 0, stream>>>(
        hbuf, BigW + (size_t)l * 128 * PW, P,
        NN, 128, PW, 128, PW, PW);
    // fused per-node attention + max + bias
    attn_kernel<<<NN, 256, 0, stream>>>(edge, hbuf, P, cvo, cc, boS,
                                        l ? b2f : b1f, l, res);
    // pairnorm stats
    reduce_kernel<<<256, 256, 0, stream>>>(res, part);
    finalize_kernel<<<1, 128, 0, stream>>>(part, l ? st1 : st0);
    if (l == 0) {
      norm_relu_kernel<<<NN * 128 / 256, 256, 0, stream>>>(res, st0, ubuf);
    } else {
      final_kernel<<<NN * 128 / 256, 256, 0, stream>>>(res, st1, xf, d_out, flagp);
    }
  }
}

// Round 3
// 827.127 us; speedup vs baseline: 1.6112x; 1.6112x over previous
//
#include <hip/hip_runtime.h>
#include <hip/hip_bf16.h>

#define NN 32768
#define DEG 8
#define PW 552          // P table row width (elements)
#define PTW 556         // padded LDS width for P tile

typedef unsigned short u16;
typedef unsigned int u32;

__device__ __forceinline__ float bf2f(u32 lo16) { return __uint_as_float(lo16 << 16); }

// ---------------- dtype detection ----------------
__global__ void detect_kernel(const void* __restrict__ x, int* __restrict__ flagp) {
  if (threadIdx.x == 0) {
    const u16* u = (const u16*)x;
    int insane = 0;
    for (int i = 0; i < 128; ++i) {
      int e = (u[i] >> 7) & 0xff;
      if (e == 0 || e == 0xff || e < 0x70 || e > 0x8f) insane++;
    }
    *flagp = (insane >= 16) ? 0 : 1;   // 1 = bf16 inputs, 0 = f32 inputs
  }
}

// ---------------- input conversion ----------------
__global__ void cvt_kernel(const void* __restrict__ src, float* __restrict__ dst, int n,
                           const int* __restrict__ flagp) {
  const int f = *flagp;
  for (int i = blockIdx.x * 256 + threadIdx.x; i < n; i += gridDim.x * 256) {
    if (f) dst[i] = bf2f((u32)((const u16*)src)[i]);
    else   dst[i] = ((const float*)src)[i];
  }
}

// ---------------- derived small tables (one block per head) ----------------
__global__ __launch_bounds__(256) void derive_small_kernel(
    const float* __restrict__ qw, const float* __restrict__ qb,
    const float* __restrict__ ow, const float* __restrict__ ob,
    float* __restrict__ cq, float* __restrict__ ck, float* __restrict__ cvo,
    float* __restrict__ cc, float* __restrict__ bo_sum) {
  const int hd = blockIdx.x;                // 0..3
  const float* Wq = qw + (size_t)(hd*3 + 0) * 18769;
  const float* Wk = qw + (size_t)(hd*3 + 1) * 18769;
  const float* Wv = qw + (size_t)(hd*3 + 2) * 18769;
  const float* bq = qb + (hd*3 + 0) * 137;
  const float* bk = qb + (hd*3 + 1) * 137;
  const float* bv = qb + (hd*3 + 2) * 137;
  const float* Wo = ow + (size_t)hd * 18769;
  const int tid = threadIdx.x;

  for (int idx = tid; idx < 9*137; idx += 256) {
    int s = idx / 137, e = idx % 137;
    cq[hd*1233 + idx] = Wq[e*137 + 128 + s] + bq[e];
    ck[hd*1233 + idx] = Wk[e*137 + 128 + s] + bk[e];
  }
  __syncthreads();   // cc below reads cq/ck

  for (int idx = tid; idx < 9*128; idx += 256) {
    int s = idx >> 7, oi = idx & 127;
    float a = 0.f;
    for (int e = 0; e < 137; ++e) a += Wo[oi*137 + e] * (Wv[e*137 + 128 + s] + bv[e]);
    cvo[hd*1152 + idx] = a;
  }
  for (int idx = tid; idx < 81; idx += 256) {
    int i = idx / 9, j = idx % 9;
    float a = 0.f;
    for (int e = 0; e < 137; ++e) a += cq[hd*1233 + i*137 + e] * ck[hd*1233 + j*137 + e];
    cc[hd*81 + idx] = a;
  }
  if ((hd & 1) == 0) {
    int l = hd >> 1;
    for (int oi = tid; oi < 128; oi += 256)
      bo_sum[l*128 + oi] = ob[(l*2 + 0)*137 + oi] + ob[(l*2 + 1)*137 + oi];
  }
}

// ---------------- Mqk / Mvo (grid 64 x 4 heads, 1 thread per element) ----------------
__global__ __launch_bounds__(256) void derive_mm_kernel(
    const float* __restrict__ qw, const float* __restrict__ ow,
    float* __restrict__ Mqk, float* __restrict__ Mvo) {
  const int hd = blockIdx.y;
  const float* Wq = qw + (size_t)(hd*3 + 0) * 18769;
  const float* Wk = qw + (size_t)(hd*3 + 1) * 18769;
  const float* Wv = qw + (size_t)(hd*3 + 2) * 18769;
  const float* Wo = ow + (size_t)hd * 18769;
  const int idx = blockIdx.x * 256 + threadIdx.x;   // 0..16383
  const int row = idx >> 7, col = idx & 127;
  float sq = 0.f, so = 0.f;
  #pragma unroll 4
  for (int e = 0; e < 137; ++e) {
    sq += Wq[e*137 + row] * Wk[e*137 + col];     // Mqk[c][c']
    so += Wo[row*137 + e] * Wv[e*137 + col];     // Mvo[oi][c]
  }
  Mqk[hd*16384 + idx] = sq;
  Mvo[hd*16384 + idx] = so;
}

// BigW[l][k][col], 128 x PW per layer
__global__ void bigw_kernel(const float* __restrict__ qw,
                            const float* __restrict__ Mqk, const float* __restrict__ Mvo,
                            const float* __restrict__ cq, const float* __restrict__ ck,
                            float* __restrict__ BigW) {
  const int idx = blockIdx.x * 256 + threadIdx.x;
  if (idx >= 2 * 128 * PW) return;
  const int l = idx / (128 * PW);
  const int r = idx % (128 * PW);
  const int k = r / PW, col = r % PW;
  float v = 0.f;
  if (col < 128)       v = Mqk[(l*2 + 0)*16384 + k*128 + col];
  else if (col < 256)  v = Mvo[(l*2 + 0)*16384 + (col - 128)*128 + k];
  else if (col < 384)  v = Mqk[(l*2 + 1)*16384 + k*128 + (col - 256)];
  else if (col < 512)  v = Mvo[(l*2 + 1)*16384 + (col - 384)*128 + k];
  else if (col < 530) {                       // qk_q: Hq_t . ck[t][j], linear in h
    int t = (col - 512) / 9, j = (col - 512) % 9;
    const float* Wq = qw + (size_t)((l*2 + t)*3 + 0) * 18769;
    const float* ckp = ck + (l*2 + t)*1233 + j*137;
    float a = 0.f;
    for (int e = 0; e < 137; ++e) a += Wq[e*137 + k] * ckp[e];
    v = a;
  } else if (col < 548) {                     // qk_k: cq[t][i] . Hk_t
    int t = (col - 530) / 9, i = (col - 530) % 9;
    const float* Wk_ = qw + (size_t)((l*2 + t)*3 + 1) * 18769;
    const float* cqp = cq + (l*2 + t)*1233 + i*137;
    float a = 0.f;
    for (int e = 0; e < 137; ++e) a += cqp[e] * Wk_[e*137 + k];
    v = a;
  }
  BigW[idx] = v;
}

// ---------------- generic f32 GEMM: C = A(MxK) @ B(KxNC), f32 out ----------------
__global__ __launch_bounds__(256) void gemm_kernel(
    const float* __restrict__ A, const float* __restrict__ B,
    float* __restrict__ C,
    int M, int K, int NC, int lda, int ldb, int ldc) {
  __shared__ float As[64][33];
  __shared__ float Bs[32][68];
  const int row0 = blockIdx.y * 64, col0 = blockIdx.x * 64;
  const int tid = threadIdx.x;
  const int tx = tid & 15, ty = tid >> 4;
  float acc[4][4] = {};
  for (int k0 = 0; k0 < K; k0 += 32) {
    {
      const int ka = tid & 31, ra = tid >> 5;
      const int kg = k0 + ka;
      #pragma unroll
      for (int p = 0; p < 8; ++p) {
        const int r = ra * 8 + p;
        As[r][ka] = (kg < K) ? A[(size_t)(row0 + r) * lda + kg] : 0.f;
      }
      const int cb = tid & 63, kb = tid >> 6;
      const int cg = col0 + cb;
      #pragma unroll
      for (int p = 0; p < 8; ++p) {
        const int kk = kb * 8 + p;
        const int kg2 = k0 + kk;
        Bs[kk][cb] = (kg2 < K && cg < NC) ? B[(size_t)kg2 * ldb + cg] : 0.f;
      }
    }
    __syncthreads();
    #pragma unroll
    for (int kk = 0; kk < 32; ++kk) {
      const float4 b4 = *(const float4*)&Bs[kk][tx * 4];
      float a[4];
      #pragma unroll
      for (int i = 0; i < 4; ++i) a[i] = As[ty*4 + i][kk];
      #pragma unroll
      for (int i = 0; i < 4; ++i) {
        acc[i][0] += a[i] * b4.x;
        acc[i][1] += a[i] * b4.y;
        acc[i][2] += a[i] * b4.z;
        acc[i][3] += a[i] * b4.w;
      }
    }
    __syncthreads();
  }
  #pragma unroll
  for (int i = 0; i < 4; ++i) {
    const int rr = row0 + ty*4 + i;
    #pragma unroll
    for (int j = 0; j < 4; ++j) {
      const int c = col0 + tx*4 + j;
      if (c < NC) C[(size_t)rr * ldc + c] = acc[i][j];
    }
  }
}

// ---------------- per-node fused attention ----------------
__global__ __launch_bounds__(256) void attn_kernel(
    const int* __restrict__ src, const float* __restrict__ hG, const float* __restrict__ PG,
    const float* __restrict__ cvo, const float* __restrict__ cc,
    const float* __restrict__ bo_sum, const float* __restrict__ b_layer,
    int layer, float* __restrict__ res) {
  __shared__ float Pt[9][PTW];
  __shared__ float hs[9][132];
  __shared__ float As[2][9][9];
  __shared__ float ymax[2][128];
  __shared__ int nbr[9];
  const int n = blockIdx.x;
  const int tid = threadIdx.x;
  if (tid < 9) nbr[tid] = (tid < 8) ? src[n * DEG + tid] : n;
  __syncthreads();
  for (int idx = tid; idx < 9 * 32; idx += 256) {
    const int s = idx >> 5, w = idx & 31;
    *(float4*)&hs[s][w * 4] = *(const float4*)(hG + (size_t)nbr[s] * 128 + w * 4);
  }
  for (int idx = tid; idx < 9 * 138; idx += 256) {
    const int s = idx / 138, w = idx % 138;
    *(float4*)&Pt[s][w * 4] = *(const float4*)(PG + (size_t)nbr[s] * PW + w * 4);
  }
  __syncthreads();
  if (tid < 162) {
    const int t = tid / 81, r = tid % 81, i = r / 9, j = r % 9;
    const float* hm = &Pt[i][t * 256];
    const float* hj = &hs[j][0];
    float s = 0.f;
    #pragma unroll 8
    for (int c = 0; c < 128; c += 4) {
      const float4 a = *(const float4*)&hm[c];
      const float4 b = *(const float4*)&hj[c];
      s += a.x * b.x + a.y * b.y + a.z * b.z + a.w * b.w;
    }
    s += Pt[i][512 + t*9 + j] + Pt[j][530 + t*9 + i] + cc[(layer*2 + t)*81 + i*9 + j];
    As[t][i][j] = s * 0.08543576577f;   // 1/sqrt(137)
  }
  __syncthreads();
  if (tid < 18) {
    const int t = tid / 9, i = tid % 9;
    float m = -3e38f;
    #pragma unroll
    for (int j = 0; j < 9; ++j) m = fmaxf(m, As[t][i][j]);
    float ex[9], ssum = 0.f;
    #pragma unroll
    for (int j = 0; j < 9; ++j) { ex[j] = expf(As[t][i][j] - m); ssum += ex[j]; }
    const float inv = 1.f / ssum;
    #pragma unroll
    for (int j = 0; j < 9; ++j) As[t][i][j] = ex[j] * inv;
  }
  __syncthreads();
  {
    const int oi = tid & 127, half = tid >> 7;
    const float* cvo1 = cvo + (layer*2 + 0)*1152 + oi;
    const float* cvo2 = cvo + (layer*2 + 1)*1152 + oi;
    float vg1[9], vg2[9];
    #pragma unroll
    for (int j = 0; j < 9; ++j) {
      vg1[j] = Pt[j][128 + oi] + cvo1[j * 128];
      vg2[j] = Pt[j][384 + oi] + cvo2[j * 128];
    }
    float mx = -3e38f;
    const int i0 = half ? 5 : 0, i1 = half ? 9 : 5;
    for (int i = i0; i < i1; ++i) {
      float y = hs[i][oi];
      #pragma unroll
      for (int j = 0; j < 9; ++j)
        y += As[0][i][j] * vg1[j] + As[1][i][j] * vg2[j];
      mx = fmaxf(mx, y);
    }
    ymax[half][oi] = mx;
  }
  __syncthreads();
  if (tid < 128) {
    const float v = fmaxf(ymax[0][tid], ymax[1][tid]) + bo_sum[layer*128 + tid] + b_layer[tid];
    res[(size_t)n * 128 + tid] = v;
  }
}

// ---------------- pairnorm reductions ----------------
__global__ __launch_bounds__(256) void reduce_kernel(const float* __restrict__ res,
                                                     float* __restrict__ partial) {
  __shared__ float col2[128];
  __shared__ float sqs[256];
  const int b = blockIdx.x, tid = threadIdx.x;
  const int c = tid & 127, half = tid >> 7;
  float cs = 0.f, sq = 0.f;
  const int r0 = half * 64;
  for (int r = r0; r < r0 + 64; ++r) {
    const float v = res[((size_t)b * 128 + r) * 128 + c];
    cs += v; sq += v * v;
  }
  if (half) col2[c] = cs;
  sqs[tid] = sq;
  __syncthreads();
  if (!half) partial[b * 129 + c] = cs + col2[c];
  for (int s = 128; s >= 1; s >>= 1) {
    if (tid < s) sqs[tid] += sqs[tid + s];
    __syncthreads();
  }
  if (tid == 0) partial[b * 129 + 128] = sqs[0];
}

__global__ __launch_bounds__(128) void finalize_kernel(const float* __restrict__ partial,
                                                       float* __restrict__ stats) {
  __shared__ float musq[128];
  __shared__ float sqs[128];
  const int tid = threadIdx.x;
  float cs = 0.f;
  for (int b = 0; b < 256; ++b) cs += partial[b * 129 + tid];
  const float m = cs * (1.f / 32768.f);
  stats[tid] = m;
  musq[tid] = m * m;
  float sq = 0.f;
  for (int b = tid; b < 256; b += 128) sq += partial[b * 129 + 128];
  sqs[tid] = sq;
  __syncthreads();
  for (int s = 64; s >= 1; s >>= 1) {
    if (tid < s) { musq[tid] += musq[tid + s]; sqs[tid] += sqs[tid + s]; }
    __syncthreads();
  }
  if (tid == 0) {
    const float meansq = sqs[0] * (1.f / 32768.f);
    const float var = meansq - musq[0];
    stats[128] = 1.f / sqrtf(1e-6f + var);
  }
}

__global__ void norm_relu_kernel(const float* __restrict__ res, const float* __restrict__ stats,
                                 float* __restrict__ u) {
  const int idx = blockIdx.x * 256 + threadIdx.x;
  const int c = idx & 127;
  const float v = (res[idx] - stats[c]) * stats[128];
  u[idx] = fmaxf(v, 0.f);
}

__global__ void final_kernel(const float* __restrict__ res, const float* __restrict__ stats,
                             const float* __restrict__ xf, void* __restrict__ out,
                             const int* __restrict__ flagp) {
  const int idx = blockIdx.x * 256 + threadIdx.x;
  const int nrow = idx >> 7, c = idx & 127;
  float v = fmaxf((res[idx] - stats[c]) * stats[128], 0.f);
  v += xf[(size_t)nrow * 130 + c];
  if (c == 127 && (v > 1.f || v < -1.f)) v = 0.f;
  v *= 0.5f;
  if (*flagp) ((__hip_bfloat16*)out)[idx] = __float2bfloat16(v);
  else        ((float*)out)[idx] = v;
}

// ---------------- host ----------------
extern "C" void kernel_launch(void* const* d_in, const int* in_sizes, int n_in,
                              void* d_out, int out_size, void* d_ws, size_t ws_size,
                              hipStream_t stream) {
  (void)in_sizes; (void)n_in; (void)out_size; (void)ws_size;
  char* ws = (char*)d_ws;
  size_t off = 0;
  auto alloc = [&](size_t bytes) -> char* {
    char* p = ws + off;
    off += (bytes + 255) & ~(size_t)255;
    return p;
  };
  int*   flagp = (int*)  alloc(4);
  float* xf    = (float*)alloc((size_t)NN * 130 * 4);
  float* W1f   = (float*)alloc(130 * 128 * 4);
  float* b1f   = (float*)alloc(128 * 4);
  float* W2f   = (float*)alloc(128 * 128 * 4);
  float* b2f   = (float*)alloc(128 * 4);
  float* qwf   = (float*)alloc((size_t)225228 * 4);
  float* qbf   = (float*)alloc(1644 * 4);
  float* owf   = (float*)alloc((size_t)75076 * 4);
  float* obf   = (float*)alloc(548 * 4);
  float* Mqk   = (float*)alloc((size_t)4 * 16384 * 4);
  float* Mvo   = (float*)alloc((size_t)4 * 16384 * 4);
  float* cq    = (float*)alloc((size_t)4 * 1233 * 4);
  float* ck    = (float*)alloc((size_t)4 * 1233 * 4);
  float* cvo   = (float*)alloc((size_t)4 * 1152 * 4);
  float* cc    = (float*)alloc((size_t)4 * 81 * 4);
  float* boS   = (float*)alloc((size_t)2 * 128 * 4);
  float* BigW  = (float*)alloc((size_t)2 * 128 * PW * 4);
  float* hbuf  = (float*)alloc((size_t)NN * 128 * 4);
  float* P     = (float*)alloc((size_t)NN * PW * 4);
  float* res   = (float*)alloc((size_t)NN * 128 * 4);
  float* ubuf  = (float*)alloc((size_t)NN * 128 * 4);
  float* part  = (float*)alloc((size_t)256 * 129 * 4);
  float* st0   = (float*)alloc(132 * 4);
  float* st1   = (float*)alloc(132 * 4);

  const int* edge = (const int*)d_in[1];   // row 0 = src

  detect_kernel<<<1, 64, 0, stream>>>(d_in[0], flagp);

  struct CvtDesc { const void* src; float* dst; int n; };
  const CvtDesc cv[9] = {
    { d_in[0], xf,  NN * 130 },
    { d_in[2], W1f, 130 * 128 },
    { d_in[3], b1f, 128 },
    { d_in[4], W2f, 128 * 128 },
    { d_in[5], b2f, 128 },
    { d_in[6], qwf, 225228 },
    { d_in[7], qbf, 1644 },
    { d_in[8], owf, 75076 },
    { d_in[9], obf, 548 },
  };
  for (int i = 0; i < 9; ++i) {
    int blocks = (cv[i].n + 255) / 256;
    if (blocks > 4096) blocks = 4096;
    cvt_kernel<<<blocks, 256, 0, stream>>>(cv[i].src, cv[i].dst, cv[i].n, flagp);
  }

  derive_small_kernel<<<4, 256, 0, stream>>>(qwf, qbf, owf, obf, cq, ck, cvo, cc, boS);
  derive_mm_kernel<<<dim3(64, 4), 256, 0, stream>>>(qwf, owf, Mqk, Mvo);
  bigw_kernel<<<(2 * 128 * PW + 255) / 256, 256, 0, stream>>>(qwf, Mqk, Mvo, cq, ck, BigW);

  for (int l = 0; l < 2; ++l) {
    const float* act = l ? ubuf : xf;
    const int K = l ? 128 : 130;
    const float* W = l ? W2f : W1f;
    // h = act @ W
    gemm_kernel<<<dim3(2, 512), 256, 0, stream>>>(act, W, hbuf,
                                                  NN, K, 128, K, 128, 128);
    // P = h @ BigW_l   (f32 out)
    gemm_kernel<<<dim3((PW + 63) / 64, 512), 256, 0, stream>>>(
        hbuf, BigW + (size_t)l * 128 * PW, P,
        NN, 128, PW, 128, PW, PW);
    // fused per-node attention + max + bias
    attn_kernel<<<NN, 256, 0, stream>>>(edge, hbuf, P, cvo, cc, boS,
                                        l ? b2f : b1f, l, res);
    // pairnorm stats
    reduce_kernel<<<256, 256, 0, stream>>>(res, part);
    finalize_kernel<<<1, 128, 0, stream>>>(part, l ? st1 : st0);
    if (l == 0) {
      norm_relu_kernel<<<NN * 128 / 256, 256, 0, stream>>>(res, st0, ubuf);
    } else {
      final_kernel<<<NN * 128 / 256, 256, 0, stream>>>(res, st1, xf, d_out, flagp);
    }
  }
}